// Round 6
// baseline (682.578 us; speedup 1.0000x reference)
//
#include <hip/hip_runtime.h>
#include <stdint.h>

#define T_ 512
#define B_ 32
#define V_ 512
#define L_ 128
#define NEGF (-1000000000.0f)

// Signed-i8 quantization: E = exp(trans) in ~[0.55,1.83]; SE*1.83 < 127.
#define SE_Q 69.0f
#define SU_Q 127.0f
#define LOGC 9.078313f   /* log(SE_Q * SU_Q) */

typedef int v4i __attribute__((ext_vector_type(4)));

// ---- DPP helpers (VALU pipe) ----------------------------------------------
template <int CTRL>
__device__ __forceinline__ int dppmov(int old_, int src) {
    return __builtin_amdgcn_update_dpp(old_, src, CTRL, 0xF, 0xF, false);
}
__device__ __forceinline__ float wave_max64(float x) {
    int xi = __float_as_int(x);
    x = fmaxf(x, __int_as_float(dppmov<0x111>(xi, xi))); xi = __float_as_int(x);
    x = fmaxf(x, __int_as_float(dppmov<0x112>(xi, xi))); xi = __float_as_int(x);
    x = fmaxf(x, __int_as_float(dppmov<0x114>(xi, xi))); xi = __float_as_int(x);
    x = fmaxf(x, __int_as_float(dppmov<0x118>(xi, xi))); xi = __float_as_int(x);
    x = fmaxf(x, __int_as_float(dppmov<0x142>(xi, xi))); xi = __float_as_int(x);
    x = fmaxf(x, __int_as_float(dppmov<0x143>(xi, xi)));
    return x;   // fully reduced in lane 63
}
__device__ __forceinline__ float wave_sum64(float x) {
    int xi = __float_as_int(x);
    x = x + __int_as_float(dppmov<0x111>(xi, xi)); xi = __float_as_int(x);
    x = x + __int_as_float(dppmov<0x112>(xi, xi)); xi = __float_as_int(x);
    x = x + __int_as_float(dppmov<0x114>(xi, xi)); xi = __float_as_int(x);
    x = x + __int_as_float(dppmov<0x118>(xi, xi)); xi = __float_as_int(x);
    x = x + __int_as_float(dppmov<0x142>(xi, xi)); xi = __float_as_int(x);
    x = x + __int_as_float(dppmov<0x143>(xi, xi));
    return x;
}
// monotonic float<->uint for LDS atomicMax (epilogue only)
__device__ __forceinline__ unsigned fkey(float f) {
    unsigned u = __float_as_uint(f);
    return (u & 0x80000000u) ? ~u : (u | 0x80000000u);
}
__device__ __forceinline__ float funkey(unsigned k) {
    unsigned u = (k & 0x80000000u) ? (k ^ 0x80000000u) : ~k;
    return __uint_as_float(u);
}

// ---------------- prep: quantize E into MFMA A-fragment layout (4-wave) -----
// asg_main thread tid (256 thr): w=tid>>6 (0..3), lane=tid&63, q=lane>>4,
// n=lane&15. Wave w owns rows 128w..128w+127 as 8 M-tiles (tt) x 8 K-tiles.
// A-frag (tt,kt): lane holds A[m=128w+16tt+n][k=64kt+16q+4d+b], d,b in 0..3.
// Flat dword o = ((tt*8+kt)*256 + tid)*4 + d.
__global__ void asg_prep(const float* __restrict__ trans, uint32_t* __restrict__ Et) {
    int o = blockIdx.x * blockDim.x + threadIdx.x;      // 0 .. 65535
    int d    = o & 3;
    int tid  = (o >> 2) & 255;
    int qreg = o >> 10;                                  // 0..63 = tt*8+kt
    int tt = qreg >> 3, kt = qreg & 7;
    int w = tid >> 6, lane = tid & 63;
    int q = lane >> 4, n = lane & 15;
    int m  = 128 * w + 16 * tt + n;
    int k0 = 64 * kt + 16 * q + 4 * d;
    const float* tp = trans + (size_t)m * V_ + k0;
    uint32_t q0 = (uint32_t)fminf(127.0f, __expf(tp[0]) * SE_Q + 0.5f);
    uint32_t q1 = (uint32_t)fminf(127.0f, __expf(tp[1]) * SE_Q + 0.5f);
    uint32_t q2 = (uint32_t)fminf(127.0f, __expf(tp[2]) * SE_Q + 0.5f);
    uint32_t q3 = (uint32_t)fminf(127.0f, __expf(tp[3]) * SE_Q + 0.5f);
    Et[(size_t)o] = q0 | (q1 << 8) | (q2 << 16) | (q3 << 24);
}

// ---------------- fused main: blocks 0..31 = FCC(b), 32..63 = FAC(b-32) -----
// FCC, 4-wave variant of the validated R2 structure: 256 threads, 1 wave/SIMD,
// each thread owns TWO adjacent rows (i0 even, i0+1). Per step:
//   wave max (pair-fmax + DPP chain) -> mw_lds[w] (4 slots) -> barrier A ->
//   kmax = one float4 read + 3-fmax tree -> u8 quantize both rows, u16 pack,
//   one DPP pair-merge, store from even lanes -> barrier B -> 8 ds_read_b128
//   B-frags -> 64 x v_mfma_i32_16x16x64_i8 (8 independent acc chains) ->
//   30-cndmask ownership mux -> explicit alpha update (R2 numerics exactly).
// Halves barrier width (4 waves), LDS pipe traffic (32 b128/step), and the
// redundant per-SIMD exchange issue vs the 8-wave version.
__global__ __attribute__((amdgpu_flat_work_group_size(256, 256),
                          amdgpu_waves_per_eu(1, 1)))
void asg_main(
    const float* __restrict__ lp, const uint32_t* __restrict__ Et,
    const float* __restrict__ trans, const int* __restrict__ targets,
    const int* __restrict__ ilen, const int* __restrict__ tlen,
    float* __restrict__ fcc_ws, float* __restrict__ fac_ws)
{
    __shared__ float facb[256];                       // fac double buffer
    __shared__ __align__(16) uint32_t u_lds[128];     // u8[512] by row index
    __shared__ __align__(16) float mw_lds[4];         // per-wave maxes
    __shared__ unsigned mslotE;
    __shared__ float sumf;

    const int bb  = blockIdx.x;
    const int tid = threadIdx.x;

    if (bb < B_) {
        // ================= FCC ============================================
        const int b    = bb;
        const int lane = tid & 63;
        const int w    = tid >> 6;              // wave 0..3, rows 128w..+127
        const int q    = lane >> 4;             // 0..3
        const int n    = lane & 15;             // 0..15
        const int tt_o = n >> 1;                // owned tile 0..7
        const int i0   = 128 * w + 16 * tt_o + 4 * q + 2 * (n & 1); // even row
        const int Tlen = ilen[b];

        // er: 64 uint4 A-frags, lane-coalesced one-time load (dumb loads ->
        // AGPR-resident on gfx950's unified file; MFMA reads A from AGPR)
        uint4 er[64];
        {
            const uint4* Eq = (const uint4*)Et;
            #pragma unroll
            for (int j = 0; j < 64; ++j) er[j] = Eq[j * 256 + tid];
        }

        float2 a0v = *(const float2*)&lp[(size_t)b * V_ + i0];
        float alpha0 = a0v.x, alpha1 = a0v.y;
        float2 lv = *(const float2*)&lp[(size_t)(B_ * V_) + (size_t)b * V_ + i0];
        float lpv0 = lv.x, lpv1 = lv.y;
        if (tid == 0) { mslotE = 0u; sumf = 0.0f; }
        __syncthreads();

        for (int t = 1; t < Tlen; ++t) {
            // ---- publish wave max over this wave's 128 rows
            {
                float mx = wave_max64(fmaxf(alpha0, alpha1));
                if (lane == 63) mw_lds[w] = mx;
            }
            __syncthreads();                           // [mw visible]

            // ---- global max: one float4 read + 3-fmax tree
            float4 mq = *(const float4*)&mw_lds[0];
            float m = fmaxf(fmaxf(mq.x, mq.y), fmaxf(mq.z, mq.w));

            // ---- u8 quantize both rows; pack u16; pair-merge (DPP 0xB1);
            //      even lanes store dword of rows 4j..4j+3
            {
                float u0 = __expf(alpha0 - m);         // <= 1
                float u1 = __expf(alpha1 - m);
                uint32_t q0 = (uint32_t)(u0 * SU_Q + 0.5f);
                uint32_t q1 = (uint32_t)(u1 * SU_Q + 0.5f);
                int u16o = (int)(q0 | (q1 << 8));
                int pr = dppmov<0xB1>(u16o, u16o);     // partner lane's u16
                if ((n & 1) == 0)
                    u_lds[32 * w + 4 * (n >> 1) + q] = (uint32_t)(u16o | (pr << 16));
            }
            __syncthreads();                           // [u visible]

            // ---- B-frags: kt-th uint4 at byte 64kt + 16q (u8[k], all cols)
            uint4 bf[8];
            #pragma unroll
            for (int kt = 0; kt < 8; ++kt)
                bf[kt] = *(const uint4*)((const char*)u_lds + 64 * kt + 16 * q);

            // prefetch next lp pair (hidden under the MFMA phase)
            int tn = (t + 1 < Tlen) ? (t + 1) : t;
            float2 lvn = *(const float2*)&lp[(size_t)tn * (B_ * V_) + (size_t)b * V_ + i0];

            // ---- 64 MFMA: A_tt += er(tt,kt) x B(kt), 8 independent chains
            v4i A0, A1, A2, A3, A4, A5, A6, A7;
            {
                v4i z = {0, 0, 0, 0};
                A0 = z; A1 = z; A2 = z; A3 = z; A4 = z; A5 = z; A6 = z; A7 = z;
            }
            #pragma unroll
            for (int kt = 0; kt < 8; ++kt) {
                v4i bv = __builtin_bit_cast(v4i, bf[kt]);
                A0 = __builtin_amdgcn_mfma_i32_16x16x64_i8(
                        __builtin_bit_cast(v4i, er[0 * 8 + kt]), bv, A0, 0, 0, 0);
                A1 = __builtin_amdgcn_mfma_i32_16x16x64_i8(
                        __builtin_bit_cast(v4i, er[1 * 8 + kt]), bv, A1, 0, 0, 0);
                A2 = __builtin_amdgcn_mfma_i32_16x16x64_i8(
                        __builtin_bit_cast(v4i, er[2 * 8 + kt]), bv, A2, 0, 0, 0);
                A3 = __builtin_amdgcn_mfma_i32_16x16x64_i8(
                        __builtin_bit_cast(v4i, er[3 * 8 + kt]), bv, A3, 0, 0, 0);
                A4 = __builtin_amdgcn_mfma_i32_16x16x64_i8(
                        __builtin_bit_cast(v4i, er[4 * 8 + kt]), bv, A4, 0, 0, 0);
                A5 = __builtin_amdgcn_mfma_i32_16x16x64_i8(
                        __builtin_bit_cast(v4i, er[5 * 8 + kt]), bv, A5, 0, 0, 0);
                A6 = __builtin_amdgcn_mfma_i32_16x16x64_i8(
                        __builtin_bit_cast(v4i, er[6 * 8 + kt]), bv, A6, 0, 0, 0);
                A7 = __builtin_amdgcn_mfma_i32_16x16x64_i8(
                        __builtin_bit_cast(v4i, er[7 * 8 + kt]), bv, A7, 0, 0, 0);
            }

            // ---- ownership mux: rows i0 (reg=2(n&1)) and i0+1 of tile tt_o
            const bool nb = (n & 1) != 0;
            int p00 = nb ? A0.z : A0.x, p10 = nb ? A0.w : A0.y;
            int p01 = nb ? A1.z : A1.x, p11 = nb ? A1.w : A1.y;
            int p02 = nb ? A2.z : A2.x, p12 = nb ? A2.w : A2.y;
            int p03 = nb ? A3.z : A3.x, p13 = nb ? A3.w : A3.y;
            int p04 = nb ? A4.z : A4.x, p14 = nb ? A4.w : A4.y;
            int p05 = nb ? A5.z : A5.x, p15 = nb ? A5.w : A5.y;
            int p06 = nb ? A6.z : A6.x, p16 = nb ? A6.w : A6.y;
            int p07 = nb ? A7.z : A7.x, p17 = nb ? A7.w : A7.y;
            const bool t0b = (tt_o & 1) != 0;
            const bool t1b = (tt_o & 2) != 0;
            const bool t2b = (tt_o & 4) != 0;
            int q00 = t0b ? p01 : p00, q01 = t0b ? p03 : p02;
            int q02 = t0b ? p05 : p04, q03 = t0b ? p07 : p06;
            int q10 = t0b ? p11 : p10, q11 = t0b ? p13 : p12;
            int q12 = t0b ? p15 : p14, q13 = t0b ? p17 : p16;
            int r00 = t1b ? q01 : q00, r01 = t1b ? q03 : q02;
            int r10 = t1b ? q11 : q10, r11 = t1b ? q13 : q12;
            int acc0 = t2b ? r01 : r00;
            int acc1 = t2b ? r11 : r10;

            alpha0 = lpv0 + (m - LOGC) + __logf((float)acc0);
            alpha1 = lpv1 + (m - LOGC) + __logf((float)acc1);
            lpv0 = lvn.x; lpv1 = lvn.y;
        }

        // ---- epilogue: exact f32 logsumexp over the 512 alphas
        {
            float mx = wave_max64(fmaxf(alpha0, alpha1));
            if (lane == 63) atomicMax(&mslotE, fkey(mx));
        }
        __syncthreads();
        float m2 = funkey(mslotE);
        {
            float sv = wave_sum64(__expf(alpha0 - m2) + __expf(alpha1 - m2));
            if (lane == 63) atomicAdd(&sumf, sv);
        }
        __syncthreads();
        if (tid == 0) fcc_ws[b] = m2 + __logf(sumf);
    } else {
        // ================= FAC (threads 0..127 active) =====================
        const int b = bb - B_;
        const int l = tid;
        const bool active = (l < L_);
        const int Tlen = ilen[b];
        const int Llen = tlen[b];

        const int tl  = active ? targets[b * L_ + l] : 0;
        const int tlm = (active && l > 0) ? targets[b * L_ + l - 1] : 0;
        const float ts = active ? trans[(size_t)tl * V_ + tl] : 0.0f;
        const float tp = (active && l > 0) ? trans[(size_t)tl * V_ + tlm] : 0.0f;

        float beta = (l == 0) ? lp[(size_t)b * V_ + tl] : NEGF;
        float em_next = active ? lp[(size_t)1 * (B_ * V_) + (size_t)b * V_ + tl] : 0.0f;

        for (int t = 1; t < Tlen; ++t) {
            float* buf = facb + (t & 1) * L_;
            if (active) buf[l] = beta;
            __syncthreads();
            float prev = (active && l > 0) ? buf[l - 1] : NEGF;
            float em = em_next;
            if (active && t + 1 < Tlen)
                em_next = lp[(size_t)(t + 1) * (B_ * V_) + (size_t)b * V_ + tl];
            if (active) {
                float st = beta + ts;
                float mv = prev + tp;
                float mx = fmaxf(st, mv);
                float mn = fminf(st, mv);
                beta = em + mx + log1pf(__expf(mn - mx));
            }
        }
        if (active && l == Llen - 1) fac_ws[b] = beta;
    }
}

// ---------------- combine ---------------------------------------------------
__global__ void asg_combine(const float* __restrict__ fcc_ws,
                            const float* __restrict__ fac_ws,
                            float* __restrict__ out) {
    int i = threadIdx.x;
    if (i < B_) out[i] = fcc_ws[i] - fac_ws[i];
}

extern "C" void kernel_launch(void* const* d_in, const int* in_sizes, int n_in,
                              void* d_out, int out_size, void* d_ws, size_t ws_size,
                              hipStream_t stream) {
    const float* lp      = (const float*)d_in[0];
    const float* trans   = (const float*)d_in[1];
    const int*   targets = (const int*)d_in[2];
    const int*   ilen    = (const int*)d_in[3];
    const int*   tlen    = (const int*)d_in[4];
    float* out = (float*)d_out;

    uint32_t* Et     = (uint32_t*)d_ws;                    // 65536 dwords = 256 KB
    float*    fcc_ws = (float*)((char*)d_ws + 65536 * 4);
    float*    fac_ws = fcc_ws + B_;

    hipLaunchKernelGGL(asg_prep, dim3(256), dim3(256), 0, stream, trans, Et);
    hipLaunchKernelGGL(asg_main, dim3(2 * B_), dim3(256), 0, stream,
                       lp, Et, trans, targets, ilen, tlen, fcc_ws, fac_ws);
    hipLaunchKernelGGL(asg_combine, dim3(1), dim3(64), 0, stream, fcc_ws, fac_ws, out);
}

// Round 7
// 572.920 us; speedup vs baseline: 1.1914x; 1.1914x over previous
//
#include <hip/hip_runtime.h>
#include <stdint.h>

#define T_ 512
#define B_ 32
#define V_ 512
#define L_ 128
#define NEGF (-1000000000.0f)

// Signed-i8 quantization: E = exp(trans) in ~[0.55,1.83]; SE*1.83 < 127.
#define SE_Q 69.0f
#define SU_Q 127.0f
#define LOGC 9.078313f   /* log(SE_Q * SU_Q) */

typedef int v4i __attribute__((ext_vector_type(4)));

// ---- DPP helpers (VALU pipe) ----------------------------------------------
template <int CTRL>
__device__ __forceinline__ int dppmov(int old_, int src) {
    return __builtin_amdgcn_update_dpp(old_, src, CTRL, 0xF, 0xF, false);
}
__device__ __forceinline__ float wave_max64(float x) {
    int xi = __float_as_int(x);
    x = fmaxf(x, __int_as_float(dppmov<0x111>(xi, xi))); xi = __float_as_int(x);
    x = fmaxf(x, __int_as_float(dppmov<0x112>(xi, xi))); xi = __float_as_int(x);
    x = fmaxf(x, __int_as_float(dppmov<0x114>(xi, xi))); xi = __float_as_int(x);
    x = fmaxf(x, __int_as_float(dppmov<0x118>(xi, xi))); xi = __float_as_int(x);
    x = fmaxf(x, __int_as_float(dppmov<0x142>(xi, xi))); xi = __float_as_int(x);
    x = fmaxf(x, __int_as_float(dppmov<0x143>(xi, xi)));
    return x;   // fully reduced in lane 63
}
__device__ __forceinline__ float wave_sum64(float x) {
    int xi = __float_as_int(x);
    x = x + __int_as_float(dppmov<0x111>(xi, xi)); xi = __float_as_int(x);
    x = x + __int_as_float(dppmov<0x112>(xi, xi)); xi = __float_as_int(x);
    x = x + __int_as_float(dppmov<0x114>(xi, xi)); xi = __float_as_int(x);
    x = x + __int_as_float(dppmov<0x118>(xi, xi)); xi = __float_as_int(x);
    x = x + __int_as_float(dppmov<0x142>(xi, xi)); xi = __float_as_int(x);
    x = x + __int_as_float(dppmov<0x143>(xi, xi));
    return x;
}
// monotonic float<->uint for LDS atomicMax (epilogue only)
__device__ __forceinline__ unsigned fkey(float f) {
    unsigned u = __float_as_uint(f);
    return (u & 0x80000000u) ? ~u : (u | 0x80000000u);
}
__device__ __forceinline__ float funkey(unsigned k) {
    unsigned u = (k & 0x80000000u) ? (k ^ 0x80000000u) : ~k;
    return __uint_as_float(u);
}
// select element r (0..3) of a v4i — 3 cndmask, no scratch
__device__ __forceinline__ int sel4(v4i a, int r) {
    int x0 = (r & 1) ? a.y : a.x;
    int x1 = (r & 1) ? a.w : a.z;
    return (r & 2) ? x1 : x0;
}

// Workspace layout (bytes):
//   [0, 262144)        Et      : 65536 u32, quantized E in MFMA A-frag layout
//   [262144, 262272)   fac_ws  : 32 floats
//   [262272, 262528)   flags   : prep_done (u32), fac_flag[32] (u32) - memset 0
#define WS_ET_DW     65536
#define WS_FAC_OFF   262144
#define WS_FLAG_OFF  262272

// ---------------- single fused kernel ---------------------------------------
// blocks 0..31  = FCC(b):   spin on prep_done, load er4, R2 main loop (exact),
//                           epilogue logsumexp, acquire fac_ws[b], write out[b].
// blocks 32..63 = FAC(b-32): quantize its 1/32 chunk of Et (identical rounding
//                           to the old asg_prep), release prep_done, run the
//                           FAC DP, write fac_ws[b], release fac_flag[b].
// Et A-frag layout (as before): thread tid (512): w=tid>>6, lane=tid&63,
// q=lane>>4, n=lane&15; A-frag(tt,kt): lane holds A[m=64w+16tt+n]
// [k=64kt+16q+4d+b'], flat dword o = ((tt*8+kt)*512 + tid)*4 + d.
__global__ __attribute__((amdgpu_flat_work_group_size(512, 512),
                          amdgpu_waves_per_eu(2, 2)))
void asg_fused(
    const float* __restrict__ lp,
    const float* __restrict__ trans, const int* __restrict__ targets,
    const int* __restrict__ ilen, const int* __restrict__ tlen,
    uint32_t* __restrict__ Et, float* __restrict__ fac_ws,
    unsigned* __restrict__ prep_done, unsigned* __restrict__ fac_flag,
    float* __restrict__ out)
{
    __shared__ float facb[256];                       // fac double buffer
    __shared__ __align__(16) uint32_t u_lds[128];     // u8[512] by row index
    __shared__ __align__(16) float mw_lds[8];         // per-wave maxes
    __shared__ unsigned mslotE;
    __shared__ float sumf;

    const int bb  = blockIdx.x;
    const int tid = threadIdx.x;

    if (bb < B_) {
        // ================= FCC ============================================
        const int b    = bb;
        const int lane = tid & 63;
        const int w    = tid >> 6;              // wave 0..7, rows 64w..64w+63
        const int q    = lane >> 4;             // 0..3
        const int n    = lane & 15;             // 0..15
        const int tt_o = n >> 2;                // owned tile
        const int rg_o = n & 3;                 // owned reg (row-in-4)
        const int i    = 64 * w + 16 * tt_o + 4 * q + rg_o;   // owned row
        const int Tlen = ilen[b];

        // ---- wait for the FAC blocks to finish producing Et
        if (tid == 0) {
            while (atomicAdd(prep_done, 0u) < 32u) __builtin_amdgcn_s_sleep(2);
            mslotE = 0u; sumf = 0.0f;
        }
        __syncthreads();
        __threadfence();                         // acquire Et

        // er: 32 uint4 A-frags, lane-coalesced one-time load (dumb loads ->
        // AGPR-resident on gfx950's unified file; MFMA reads A from AGPR)
        uint4 er4[32];
        {
            const uint4* Eq = (const uint4*)Et;
            #pragma unroll
            for (int t8 = 0; t8 < 32; ++t8) er4[t8] = Eq[t8 * 512 + tid];
        }

        float alpha = lp[(size_t)b * V_ + i];
        float lpv   = lp[(size_t)1 * (B_ * V_) + (size_t)b * V_ + i];
        __syncthreads();

        for (int t = 1; t < Tlen; ++t) {
            // ---- publish wave max (lane 63 holds the full reduce)
            {
                float mx = wave_max64(alpha);
                if (lane == 63) mw_lds[w] = mx;
            }
            __syncthreads();                           // [mw visible]

            // ---- global max: broadcast-read 8 wave maxes, fmax tree
            float4 m0 = *(const float4*)&mw_lds[0];
            float4 m1 = *(const float4*)&mw_lds[4];
            float m = fmaxf(fmaxf(fmaxf(m0.x, m0.y), fmaxf(m0.z, m0.w)),
                            fmaxf(fmaxf(m1.x, m1.y), fmaxf(m1.z, m1.w)));

            // ---- u8 quantized u = exp(alpha - m), quad-packed to LDS byte i
            {
                float u = __expf(alpha - m);           // <= 1
                uint32_t qu = (uint32_t)(u * SU_Q + 0.5f);
                int pv = (int)(qu << (8 * (i & 3)));   // i&3 == lane bits 0-1
                pv |= dppmov<0xB1>(pv, pv);
                pv |= dppmov<0x4E>(pv, pv);
                if ((i & 3) == 0) u_lds[i >> 2] = (uint32_t)pv;
            }
            __syncthreads();                           // [u visible]

            // ---- B-frags: kt-th uint4 at byte 64kt + 16q (u8[k], all cols)
            uint4 bf[8];
            #pragma unroll
            for (int kt = 0; kt < 8; ++kt)
                bf[kt] = *(const uint4*)((const char*)u_lds + 64 * kt + 16 * q);

            // prefetch next lp (in flight over the MFMA phase)
            int tn = (t + 1 < Tlen) ? (t + 1) : t;
            float lpv_n = lp[(size_t)tn * (B_ * V_) + (size_t)b * V_ + i];

            // ---- 32 MFMA: acc[tt] = sum_kt A(tt,kt) x B(kt)
            v4i a0, a1, a2, a3;
            {
                v4i z = {0, 0, 0, 0};
                a0 = z; a1 = z; a2 = z; a3 = z;
            }
            #pragma unroll
            for (int kt = 0; kt < 8; ++kt) {
                v4i bv = __builtin_bit_cast(v4i, bf[kt]);
                a0 = __builtin_amdgcn_mfma_i32_16x16x64_i8(
                        __builtin_bit_cast(v4i, er4[0 * 8 + kt]), bv, a0, 0, 0, 0);
                a1 = __builtin_amdgcn_mfma_i32_16x16x64_i8(
                        __builtin_bit_cast(v4i, er4[1 * 8 + kt]), bv, a1, 0, 0, 0);
                a2 = __builtin_amdgcn_mfma_i32_16x16x64_i8(
                        __builtin_bit_cast(v4i, er4[2 * 8 + kt]), bv, a2, 0, 0, 0);
                a3 = __builtin_amdgcn_mfma_i32_16x16x64_i8(
                        __builtin_bit_cast(v4i, er4[3 * 8 + kt]), bv, a3, 0, 0, 0);
            }

            // ---- ownership select: acc[tt_o][rg_o] (C: row=4q+reg, col=n)
            int s0 = sel4(a0, rg_o), s1 = sel4(a1, rg_o);
            int s2 = sel4(a2, rg_o), s3 = sel4(a3, rg_o);
            int y0 = (tt_o & 1) ? s1 : s0;
            int y1 = (tt_o & 1) ? s3 : s2;
            int acc = (tt_o & 2) ? y1 : y0;

            alpha = lpv + (m - LOGC) + __logf((float)acc);
            lpv = lpv_n;
        }

        // ---- epilogue: exact f32 logsumexp over the 512 alphas
        {
            float mx = wave_max64(alpha);
            if (lane == 63) atomicMax(&mslotE, fkey(mx));
        }
        __syncthreads();
        float m2 = funkey(mslotE);
        {
            float sv = wave_sum64(__expf(alpha - m2));
            if (lane == 63) atomicAdd(&sumf, sv);
        }
        __syncthreads();
        if (tid == 0) {
            float fcc = m2 + __logf(sumf);
            // ---- fused combine: acquire fac_ws[b] (FAC finished long ago)
            while (atomicAdd(&fac_flag[b], 0u) == 0u) __builtin_amdgcn_s_sleep(2);
            __threadfence();
            out[b] = fcc - fac_ws[b];
        }
    } else {
        // ================= FAC block: prep chunk + DP ======================
        const int b = bb - B_;

        // ---- prep: this block quantizes dwords [b*2048, (b+1)*2048) of Et,
        // identical rounding expression to the original asg_prep kernel.
        #pragma unroll
        for (int k = 0; k < 4; ++k) {
            int o = b * 2048 + k * 512 + tid;           // flat dword index
            int d    = o & 3;
            int ptid = (o >> 2) & 511;
            int qreg = o >> 11;                          // 0..31
            int tt = qreg >> 3, kt = qreg & 7;
            int pw = ptid >> 6, plane = ptid & 63;
            int pq = plane >> 4, pn = plane & 15;
            int m  = 64 * pw + 16 * tt + pn;
            int k0 = 64 * kt + 16 * pq + 4 * d;
            const float* tp = trans + (size_t)m * V_ + k0;
            uint32_t q0 = (uint32_t)fminf(127.0f, __expf(tp[0]) * SE_Q + 0.5f);
            uint32_t q1 = (uint32_t)fminf(127.0f, __expf(tp[1]) * SE_Q + 0.5f);
            uint32_t q2 = (uint32_t)fminf(127.0f, __expf(tp[2]) * SE_Q + 0.5f);
            uint32_t q3 = (uint32_t)fminf(127.0f, __expf(tp[3]) * SE_Q + 0.5f);
            Et[(size_t)o] = q0 | (q1 << 8) | (q2 << 16) | (q3 << 24);
        }
        __threadfence();                                 // release Et
        __syncthreads();
        if (tid == 0) atomicAdd(prep_done, 1u);

        // ---- FAC DP (threads 0..127 active)
        const int l = tid;
        const bool active = (l < L_);
        const int Tlen = ilen[b];
        const int Llen = tlen[b];

        const int tl  = active ? targets[b * L_ + l] : 0;
        const int tlm = (active && l > 0) ? targets[b * L_ + l - 1] : 0;
        const float ts = active ? trans[(size_t)tl * V_ + tl] : 0.0f;
        const float tp = (active && l > 0) ? trans[(size_t)tl * V_ + tlm] : 0.0f;

        float beta = (l == 0) ? lp[(size_t)b * V_ + tl] : NEGF;
        float em_next = active ? lp[(size_t)1 * (B_ * V_) + (size_t)b * V_ + tl] : 0.0f;

        for (int t = 1; t < Tlen; ++t) {
            float* buf = facb + (t & 1) * L_;
            if (active) buf[l] = beta;
            __syncthreads();
            float prev = (active && l > 0) ? buf[l - 1] : NEGF;
            float em = em_next;
            if (active && t + 1 < Tlen)
                em_next = lp[(size_t)(t + 1) * (B_ * V_) + (size_t)b * V_ + tl];
            if (active) {
                float st = beta + ts;
                float mv = prev + tp;
                float mx = fmaxf(st, mv);
                float mn = fminf(st, mv);
                beta = em + mx + log1pf(__expf(mn - mx));
            }
        }
        if (active && l == Llen - 1) {
            fac_ws[b] = beta;
            __threadfence();                             // release fac_ws[b]
            atomicExch(&fac_flag[b], 1u);
        }
    }
}

extern "C" void kernel_launch(void* const* d_in, const int* in_sizes, int n_in,
                              void* d_out, int out_size, void* d_ws, size_t ws_size,
                              hipStream_t stream) {
    const float* lp      = (const float*)d_in[0];
    const float* trans   = (const float*)d_in[1];
    const int*   targets = (const int*)d_in[2];
    const int*   ilen    = (const int*)d_in[3];
    const int*   tlen    = (const int*)d_in[4];
    float* out = (float*)d_out;

    uint32_t* Et        = (uint32_t*)d_ws;
    float*    fac_ws    = (float*)((char*)d_ws + WS_FAC_OFF);
    unsigned* prep_done = (unsigned*)((char*)d_ws + WS_FLAG_OFF);
    unsigned* fac_flag  = prep_done + 1;

    // zero the flag block (prep_done + fac_flag[32]); graph-capture-safe
    hipMemsetAsync((char*)d_ws + WS_FLAG_OFF, 0, 256, stream);

    hipLaunchKernelGGL(asg_fused, dim3(2 * B_), dim3(512), 0, stream,
                       lp, trans, targets, ilen, tlen,
                       Et, fac_ws, prep_done, fac_flag, out);
}